// Round 10
// baseline (258.741 us; speedup 1.0000x reference)
//
#include <hip/hip_runtime.h>

// FFB encoder fused kernel, MI355X (gfx950). Round 10.
//  vs round 9: deeper B pipelines (attack the ~85us stall component).
//   - GEMM1 B-stream prefetch distance 2 -> 3 (ring of 4): ~120-160 cyc of
//     latency cover vs ~200 cyc L2 hit; per-kb MFMA window is only ~40 cyc.
//   - Head GEMM: preload ALL 8 B-frags before the kb loop (32 transient
//     VGPRs, C1 dead by then) - removes the 1-deep stall every 20-cyc window.
//   - __launch_bounds__(256,4): cap VGPR at 128 (LDS already caps 4 blocks/CU
//     = 4 waves/SIMD); guards against R8-style scratch spills.
//  Kept from R9: TM=64, f16 single-product GEMMs, grid branch hi-only with
//  gf pre-scaled 2^(l-1), LDS 40960 (s_x stride-264 + s_g + pos), 2 barriers
//  per layer, head 4 m-tiles.

#define TM 64
#define XSTRIDE 264
#define GSTRIDE 48
#define K5 0.79577471545947667f         // 5/(2*pi)

typedef __attribute__((ext_vector_type(8))) _Float16 v8h;
typedef __attribute__((ext_vector_type(2))) __fp16 hw2;
typedef __attribute__((ext_vector_type(4))) float v4f;
typedef __attribute__((ext_vector_type(16))) float v16f;

#define MFMA16H(a, b, c) __builtin_amdgcn_mfma_f32_16x16x32_f16(a, b, c, 0, 0, 0)
#define MFMA32H(a, b, c) __builtin_amdgcn_mfma_f32_32x32x16_f16(a, b, c, 0, 0, 0)

__device__ __forceinline__ float sin_rev(float u) {
#if __has_builtin(__builtin_amdgcn_fractf)
    return __builtin_amdgcn_sinf(__builtin_amdgcn_fractf(u));
#else
    return __builtin_amdgcn_sinf(u - floorf(u));
#endif
}

__device__ __forceinline__ short f16s(float x) {      // RNE f32->f16
    _Float16 hh = (_Float16)x;
    return __builtin_bit_cast(short, hh);
}

// ---------------- weight packing (unchanged from R9) ----------------
// wh  f16: [l][kb16][nt8][lane64][8]  (327680 shorts), scaled by K5
// whh f16: [l][kb8][nt4][lane64][8]   (81920 shorts),  scaled by K5
// gf  f16: [l][nt8][lane64][8]        (20480 shorts),  ffnA*2^(l-1)
__global__ __launch_bounds__(256) void ffb_pack(
    const float* __restrict__ Wh, const float* __restrict__ Whh,
    const float* __restrict__ ffnA,
    short* __restrict__ wh, short* __restrict__ whh, short* __restrict__ gf)
{
    int t = blockIdx.x * 256 + threadIdx.x;
    if (t < 40960) {                       // (l, kb, nt, lane)
        int lane = t & 63, nt = (t >> 6) & 7, kb = (t >> 9) & 15, l = t >> 13;
        int n = nt * 32 + (lane & 31);
        int k0 = kb * 16 + (lane >> 5) * 8;
        short hs[8];
        #pragma unroll
        for (int jj = 0; jj < 8; jj++)
            hs[jj] = f16s(Wh[(l * 256 + k0 + jj) * 256 + n] * K5);
        *(v8h*)(wh + t * 8) = *(v8h*)hs;
    } else if (t < 51200) {
        int t2 = t - 40960;                // (l, kb, nt, lane)
        int lane = t2 & 63, nt = (t2 >> 6) & 3, kb = (t2 >> 8) & 7, l = t2 >> 11;
        int n = nt * 16 + (lane & 15);
        int k0 = kb * 32 + (lane >> 4) * 8;
        short hs[8];
        #pragma unroll
        for (int jj = 0; jj < 8; jj++)
            hs[jj] = f16s(Whh[(l * 256 + k0 + jj) * 64 + n] * K5);
        *(v8h*)(whh + t2 * 8) = *(v8h*)hs;
    } else if (t < 53760) {
        int t3 = t - 51200;                // (l, nt, lane)
        int lane = t3 & 63, nt = (t3 >> 6) & 7, l = t3 >> 9;
        int n = nt * 32 + (lane & 31);
        const float sc = 0.5f * (float)(1 << l);       // 2^(l-1), exact
        short hs[8];
        #pragma unroll
        for (int jj = 0; jj < 8; jj++)
            hs[jj] = f16s(ffnA[(l * 8 + jj) * 256 + n] * sc);
        *(v8h*)(gf + t3 * 8) = *(v8h*)hs;
    }
}

// ---------------- main fused kernel ----------------
__global__ __launch_bounds__(256, 4) void ffb_main(
    const float* __restrict__ pos, const float* __restrict__ gfeat,
    const float* __restrict__ W0, const float* __restrict__ b0,
    const float* __restrict__ bh, const float* __restrict__ bhh,
    const short* __restrict__ wh, const short* __restrict__ whh,
    const short* __restrict__ gf,
    float* __restrict__ out)
{
    __shared__ __align__(16) short s_x[TM * XSTRIDE];   // f16  (33792 B)
    __shared__ __align__(16) short s_g[TM * GSTRIDE];   // f16  (6144 B)
    __shared__ float s_pos[TM * 3];                     //      (768 B)

    const int tid = threadIdx.x;
    const int row0 = blockIdx.x * TM;
    const int lane = tid & 63;
    const int w = tid >> 6;
    const int i = lane & 15;
    const int q = lane >> 4;
    const int m32 = lane & 31;
    const int h = lane >> 5;

    if (tid < TM * 3) s_pos[tid] = pos[row0 * 3 + tid];
    for (int k2 = tid; k2 < TM * 40; k2 += 256) {
        int r = k2 / 40, f = k2 % 40;
        s_g[r * GSTRIDE + f] = f16s(gfeat[row0 * 40 + k2]);
    }
    __syncthreads();

    // layer 0: x = sin(5*(pos@W0 + b0))
    {
        const int c = tid;
        const float w00 = W0[c], w01 = W0[256 + c], w02 = W0[512 + c], bc = b0[c];
        #pragma unroll 4
        for (int r = 0; r < TM; r++) {
            float d = s_pos[r * 3 + 0] * w00 + s_pos[r * 3 + 1] * w01
                    + s_pos[r * 3 + 2] * w02 + bc;
            s_x[r * XSTRIDE + c] = f16s(sin_rev(d * K5));
        }
    }
    __syncthreads();

    float cout[4][4];
    #pragma unroll
    for (int m = 0; m < 4; m++)
        #pragma unroll
        for (int r = 0; r < 4; r++) cout[m][r] = 0.f;

    const int a1off0 = m32 * XSTRIDE + h * 8;            // m-tile 0, + kb*16
    const int a1off1 = (32 + m32) * XSTRIDE + h * 8;     // m-tile 1

    for (int l = 0; l < 5; l++) {
        // ---- bias-init C1 (pre-scaled by K5), prefetch G B-frags ----
        const float bias0 = bh[l * 256 + w * 64 + m32] * K5;
        const float bias1 = bh[l * 256 + w * 64 + 32 + m32] * K5;
        v16f C1[2][2];
        #pragma unroll
        for (int r = 0; r < 16; r++) {
            C1[0][0][r] = bias0; C1[1][0][r] = bias0;
            C1[0][1][r] = bias1; C1[1][1][r] = bias1;
        }
        v8h gb0 = *(const v8h*)(gf + ((l * 8 + w * 2 + 0) * 64 + lane) * 8);
        v8h gb1 = *(const v8h*)(gf + ((l * 8 + w * 2 + 1) * 64 + lane) * 8);

        // ---- GEMM1: 64 rows x 64 cols per wave, 3-deep B prefetch ----
        {
            const short* bp = wh + l * 65536 + (2 * w) * 512 + lane * 8;
            v8h rb0[4], rb1[4];
            #pragma unroll
            for (int p = 0; p < 3; p++) {
                rb0[p] = *(const v8h*)(bp + p * 4096);
                rb1[p] = *(const v8h*)(bp + p * 4096 + 512);
            }
            #pragma unroll
            for (int kb = 0; kb < 16; kb++) {
                if (kb + 3 < 16) {
                    rb0[(kb + 3) & 3] = *(const v8h*)(bp + (kb + 3) * 4096);
                    rb1[(kb + 3) & 3] = *(const v8h*)(bp + (kb + 3) * 4096 + 512);
                }
                v8h a0 = *(const v8h*)&s_x[a1off0 + kb * 16];
                v8h a1 = *(const v8h*)&s_x[a1off1 + kb * 16];
                v8h bc0 = rb0[kb & 3], bc1 = rb1[kb & 3];
                C1[0][0] = MFMA32H(a0, bc0, C1[0][0]);
                C1[0][1] = MFMA32H(a0, bc1, C1[0][1]);
                C1[1][0] = MFMA32H(a1, bc0, C1[1][0]);
                C1[1][1] = MFMA32H(a1, bc1, C1[1][1]);
            }
        }
        __syncthreads();   // all waves done reading x_l

        // ---- epilogue: x = sin(C1) + sin(G), G = g@(ffnA*2^l) ----
        // gf pre-scaled by 2^(l-1); both A k-halves carry g (LDS broadcast)
        // so the doubled k-sum lands on 2^l.
        #pragma unroll
        for (int m = 0; m < 2; m++) {
            v8h ga = *(const v8h*)&s_g[(m * 32 + m32) * GSTRIDE + l * 8];
            #pragma unroll
            for (int t = 0; t < 2; t++) {
                v16f Z = {};
                v16f G = MFMA32H(ga, (t ? gb1 : gb0), Z);
                const int col = w * 64 + t * 32 + m32;
                #pragma unroll
                for (int r = 0; r < 16; r++) {
                    const int row = m * 32 + (r & 3) + 8 * (r >> 2) + 4 * h;
                    float v = sin_rev(C1[m][t][r]) + sin_rev(G[r]);
                    s_x[row * XSTRIDE + col] = f16s(v);
                }
            }
        }
        __syncthreads();   // new x visible

        // ---- GEMM2: head, 64 rows x 16 cols per wave (4 m-tiles) ----
        // Full B stream (8 frags = 8 KB) preloaded; C1 is dead here so the
        // 32 transient VGPRs are free.
        const float b2 = bhh[l * 64 + w * 16 + i] * K5;
        v4f C2[4];
        #pragma unroll
        for (int m = 0; m < 4; m++) C2[m] = (v4f){b2, b2, b2, b2};
        {
            const short* bp = whh + l * 16384 + w * 512 + lane * 8;
            v8h bc[8];
            #pragma unroll
            for (int kb = 0; kb < 8; kb++)
                bc[kb] = *(const v8h*)(bp + kb * 2048);
            #pragma unroll
            for (int kb = 0; kb < 8; kb++) {
                #pragma unroll
                for (int m = 0; m < 4; m++) {
                    v8h a = *(const v8h*)&s_x[(m * 16 + i) * XSTRIDE + q * 8 + kb * 32];
                    C2[m] = MFMA16H(a, bc[kb], C2[m]);
                }
            }
        }
        #pragma unroll
        for (int m = 0; m < 4; m++)
            #pragma unroll
            for (int r = 0; r < 4; r++)
                cout[m][r] += sin_rev(C2[m][r]);
        // no barrier: next GEMM1 reads same x; overwrites after its own barrier
    }

    // ---- store x_out ----
    #pragma unroll
    for (int m = 0; m < 4; m++)
        #pragma unroll
        for (int r = 0; r < 4; r++)
            out[(row0 + m * 16 + q * 4 + r) * 64 + w * 16 + i] = cout[m][r];
}

extern "C" void kernel_launch(void* const* d_in, const int* in_sizes, int n_in,
                              void* d_out, int out_size, void* d_ws, size_t ws_size,
                              hipStream_t stream) {
    const float* pos   = (const float*)d_in[0];
    const float* gfeat = (const float*)d_in[1];
    const float* ffnA  = (const float*)d_in[2];
    const float* W0    = (const float*)d_in[3];
    const float* b0    = (const float*)d_in[4];
    const float* Wh    = (const float*)d_in[5];
    const float* bh    = (const float*)d_in[6];
    const float* Whh   = (const float*)d_in[7];
    const float* bhh   = (const float*)d_in[8];
    float* out = (float*)d_out;
    const int N = in_sizes[0] / 3;

    // ws (shorts): wh 327680 | whh 81920 | gf 20480   (0.86 MB)
    short* wh  = (short*)d_ws;
    short* whh = wh + 327680;
    short* gf  = whh + 81920;

    ffb_pack<<<210, 256, 0, stream>>>(Wh, Whh, ffnA, wh, whh, gf);
    ffb_main<<<N / TM, 256, 0, stream>>>(pos, gfeat, W0, b0, bh, bhh,
                                         wh, whh, gf, out);
}

// Round 11
// 228.950 us; speedup vs baseline: 1.1301x; 1.1301x over previous
//
#include <hip/hip_runtime.h>

// FFB encoder fused kernel, MI355X (gfx950). Round 11.
//  vs round 10: SPILL FIX — __launch_bounds__(256,3) (not 4).
//   R10 post-mortem: (256,4) capped unified VGPR+AGPR at 128/wave; C1(64) +
//   B-ring(32) + head-preload(32) + cout(16) overflowed -> scratch spills:
//   WRITE_SIZE 32.8 -> 258 MB, FETCH 14.5 -> 55.9 MB, dur 157 -> 186 us.
//   With waves/EU=3 the cap is ~170 and nothing spills (R9: 72 VGPR, clean).
//   LDS (40960 x 4 = 160 KiB exactly) stays the residency cap: 4 blocks/CU.
//  Kept from R10 (the actual experiment, now unconfounded):
//   - GEMM1 B-stream prefetch distance 3 (ring of 4): ~120-160 cyc cover.
//   - Head GEMM: all 8 B-frags preloaded before the kb loop.
//  Kept from R9: TM=64, f16 single-product GEMMs, grid branch hi-only
//  (gf pre-scaled 2^(l-1)), stride-264 LDS, 2 barriers/layer.

#define TM 64
#define XSTRIDE 264
#define GSTRIDE 48
#define K5 0.79577471545947667f         // 5/(2*pi)

typedef __attribute__((ext_vector_type(8))) _Float16 v8h;
typedef __attribute__((ext_vector_type(2))) __fp16 hw2;
typedef __attribute__((ext_vector_type(4))) float v4f;
typedef __attribute__((ext_vector_type(16))) float v16f;

#define MFMA16H(a, b, c) __builtin_amdgcn_mfma_f32_16x16x32_f16(a, b, c, 0, 0, 0)
#define MFMA32H(a, b, c) __builtin_amdgcn_mfma_f32_32x32x16_f16(a, b, c, 0, 0, 0)

__device__ __forceinline__ float sin_rev(float u) {
#if __has_builtin(__builtin_amdgcn_fractf)
    return __builtin_amdgcn_sinf(__builtin_amdgcn_fractf(u));
#else
    return __builtin_amdgcn_sinf(u - floorf(u));
#endif
}

__device__ __forceinline__ short f16s(float x) {      // RNE f32->f16
    _Float16 hh = (_Float16)x;
    return __builtin_bit_cast(short, hh);
}

// ---------------- weight packing (unchanged from R9/R10) ----------------
// wh  f16: [l][kb16][nt8][lane64][8]  (327680 shorts), scaled by K5
// whh f16: [l][kb8][nt4][lane64][8]   (81920 shorts),  scaled by K5
// gf  f16: [l][nt8][lane64][8]        (20480 shorts),  ffnA*2^(l-1)
__global__ __launch_bounds__(256) void ffb_pack(
    const float* __restrict__ Wh, const float* __restrict__ Whh,
    const float* __restrict__ ffnA,
    short* __restrict__ wh, short* __restrict__ whh, short* __restrict__ gf)
{
    int t = blockIdx.x * 256 + threadIdx.x;
    if (t < 40960) {                       // (l, kb, nt, lane)
        int lane = t & 63, nt = (t >> 6) & 7, kb = (t >> 9) & 15, l = t >> 13;
        int n = nt * 32 + (lane & 31);
        int k0 = kb * 16 + (lane >> 5) * 8;
        short hs[8];
        #pragma unroll
        for (int jj = 0; jj < 8; jj++)
            hs[jj] = f16s(Wh[(l * 256 + k0 + jj) * 256 + n] * K5);
        *(v8h*)(wh + t * 8) = *(v8h*)hs;
    } else if (t < 51200) {
        int t2 = t - 40960;                // (l, kb, nt, lane)
        int lane = t2 & 63, nt = (t2 >> 6) & 3, kb = (t2 >> 8) & 7, l = t2 >> 11;
        int n = nt * 16 + (lane & 15);
        int k0 = kb * 32 + (lane >> 4) * 8;
        short hs[8];
        #pragma unroll
        for (int jj = 0; jj < 8; jj++)
            hs[jj] = f16s(Whh[(l * 256 + k0 + jj) * 64 + n] * K5);
        *(v8h*)(whh + t2 * 8) = *(v8h*)hs;
    } else if (t < 53760) {
        int t3 = t - 51200;                // (l, nt, lane)
        int lane = t3 & 63, nt = (t3 >> 6) & 7, l = t3 >> 9;
        int n = nt * 32 + (lane & 31);
        const float sc = 0.5f * (float)(1 << l);       // 2^(l-1), exact
        short hs[8];
        #pragma unroll
        for (int jj = 0; jj < 8; jj++)
            hs[jj] = f16s(ffnA[(l * 8 + jj) * 256 + n] * sc);
        *(v8h*)(gf + t3 * 8) = *(v8h*)hs;
    }
}

// ---------------- main fused kernel ----------------
__global__ __launch_bounds__(256, 3) void ffb_main(
    const float* __restrict__ pos, const float* __restrict__ gfeat,
    const float* __restrict__ W0, const float* __restrict__ b0,
    const float* __restrict__ bh, const float* __restrict__ bhh,
    const short* __restrict__ wh, const short* __restrict__ whh,
    const short* __restrict__ gf,
    float* __restrict__ out)
{
    __shared__ __align__(16) short s_x[TM * XSTRIDE];   // f16  (33792 B)
    __shared__ __align__(16) short s_g[TM * GSTRIDE];   // f16  (6144 B)
    __shared__ float s_pos[TM * 3];                     //      (768 B)

    const int tid = threadIdx.x;
    const int row0 = blockIdx.x * TM;
    const int lane = tid & 63;
    const int w = tid >> 6;
    const int i = lane & 15;
    const int q = lane >> 4;
    const int m32 = lane & 31;
    const int h = lane >> 5;

    if (tid < TM * 3) s_pos[tid] = pos[row0 * 3 + tid];
    for (int k2 = tid; k2 < TM * 40; k2 += 256) {
        int r = k2 / 40, f = k2 % 40;
        s_g[r * GSTRIDE + f] = f16s(gfeat[row0 * 40 + k2]);
    }
    __syncthreads();

    // layer 0: x = sin(5*(pos@W0 + b0))
    {
        const int c = tid;
        const float w00 = W0[c], w01 = W0[256 + c], w02 = W0[512 + c], bc = b0[c];
        #pragma unroll 4
        for (int r = 0; r < TM; r++) {
            float d = s_pos[r * 3 + 0] * w00 + s_pos[r * 3 + 1] * w01
                    + s_pos[r * 3 + 2] * w02 + bc;
            s_x[r * XSTRIDE + c] = f16s(sin_rev(d * K5));
        }
    }
    __syncthreads();

    float cout[4][4];
    #pragma unroll
    for (int m = 0; m < 4; m++)
        #pragma unroll
        for (int r = 0; r < 4; r++) cout[m][r] = 0.f;

    const int a1off0 = m32 * XSTRIDE + h * 8;            // m-tile 0, + kb*16
    const int a1off1 = (32 + m32) * XSTRIDE + h * 8;     // m-tile 1

    for (int l = 0; l < 5; l++) {
        // ---- bias-init C1 (pre-scaled by K5), prefetch G B-frags ----
        const float bias0 = bh[l * 256 + w * 64 + m32] * K5;
        const float bias1 = bh[l * 256 + w * 64 + 32 + m32] * K5;
        v16f C1[2][2];
        #pragma unroll
        for (int r = 0; r < 16; r++) {
            C1[0][0][r] = bias0; C1[1][0][r] = bias0;
            C1[0][1][r] = bias1; C1[1][1][r] = bias1;
        }
        v8h gb0 = *(const v8h*)(gf + ((l * 8 + w * 2 + 0) * 64 + lane) * 8);
        v8h gb1 = *(const v8h*)(gf + ((l * 8 + w * 2 + 1) * 64 + lane) * 8);

        // ---- GEMM1: 64 rows x 64 cols per wave, 3-deep B prefetch ----
        {
            const short* bp = wh + l * 65536 + (2 * w) * 512 + lane * 8;
            v8h rb0[4], rb1[4];
            #pragma unroll
            for (int p = 0; p < 3; p++) {
                rb0[p] = *(const v8h*)(bp + p * 4096);
                rb1[p] = *(const v8h*)(bp + p * 4096 + 512);
            }
            #pragma unroll
            for (int kb = 0; kb < 16; kb++) {
                if (kb + 3 < 16) {
                    rb0[(kb + 3) & 3] = *(const v8h*)(bp + (kb + 3) * 4096);
                    rb1[(kb + 3) & 3] = *(const v8h*)(bp + (kb + 3) * 4096 + 512);
                }
                v8h a0 = *(const v8h*)&s_x[a1off0 + kb * 16];
                v8h a1 = *(const v8h*)&s_x[a1off1 + kb * 16];
                v8h bc0 = rb0[kb & 3], bc1 = rb1[kb & 3];
                C1[0][0] = MFMA32H(a0, bc0, C1[0][0]);
                C1[0][1] = MFMA32H(a0, bc1, C1[0][1]);
                C1[1][0] = MFMA32H(a1, bc0, C1[1][0]);
                C1[1][1] = MFMA32H(a1, bc1, C1[1][1]);
            }
        }
        __syncthreads();   // all waves done reading x_l

        // ---- epilogue: x = sin(C1) + sin(G), G = g@(ffnA*2^l) ----
        // gf pre-scaled by 2^(l-1); both A k-halves carry g (LDS broadcast)
        // so the doubled k-sum lands on 2^l.
        #pragma unroll
        for (int m = 0; m < 2; m++) {
            v8h ga = *(const v8h*)&s_g[(m * 32 + m32) * GSTRIDE + l * 8];
            #pragma unroll
            for (int t = 0; t < 2; t++) {
                v16f Z = {};
                v16f G = MFMA32H(ga, (t ? gb1 : gb0), Z);
                const int col = w * 64 + t * 32 + m32;
                #pragma unroll
                for (int r = 0; r < 16; r++) {
                    const int row = m * 32 + (r & 3) + 8 * (r >> 2) + 4 * h;
                    float v = sin_rev(C1[m][t][r]) + sin_rev(G[r]);
                    s_x[row * XSTRIDE + col] = f16s(v);
                }
            }
        }
        __syncthreads();   // new x visible

        // ---- GEMM2: head, 64 rows x 16 cols per wave (4 m-tiles) ----
        // Full B stream (8 frags) preloaded; C1 is dead here so the 32
        // transient VGPRs are free under the ~170 cap.
        const float b2 = bhh[l * 64 + w * 16 + i] * K5;
        v4f C2[4];
        #pragma unroll
        for (int m = 0; m < 4; m++) C2[m] = (v4f){b2, b2, b2, b2};
        {
            const short* bp = whh + l * 16384 + w * 512 + lane * 8;
            v8h bc[8];
            #pragma unroll
            for (int kb = 0; kb < 8; kb++)
                bc[kb] = *(const v8h*)(bp + kb * 2048);
            #pragma unroll
            for (int kb = 0; kb < 8; kb++) {
                #pragma unroll
                for (int m = 0; m < 4; m++) {
                    v8h a = *(const v8h*)&s_x[(m * 16 + i) * XSTRIDE + q * 8 + kb * 32];
                    C2[m] = MFMA16H(a, bc[kb], C2[m]);
                }
            }
        }
        #pragma unroll
        for (int m = 0; m < 4; m++)
            #pragma unroll
            for (int r = 0; r < 4; r++)
                cout[m][r] += sin_rev(C2[m][r]);
        // no barrier: next GEMM1 reads same x; overwrites after its own barrier
    }

    // ---- store x_out ----
    #pragma unroll
    for (int m = 0; m < 4; m++)
        #pragma unroll
        for (int r = 0; r < 4; r++)
            out[(row0 + m * 16 + q * 4 + r) * 64 + w * 16 + i] = cout[m][r];
}

extern "C" void kernel_launch(void* const* d_in, const int* in_sizes, int n_in,
                              void* d_out, int out_size, void* d_ws, size_t ws_size,
                              hipStream_t stream) {
    const float* pos   = (const float*)d_in[0];
    const float* gfeat = (const float*)d_in[1];
    const float* ffnA  = (const float*)d_in[2];
    const float* W0    = (const float*)d_in[3];
    const float* b0    = (const float*)d_in[4];
    const float* Wh    = (const float*)d_in[5];
    const float* bh    = (const float*)d_in[6];
    const float* Whh   = (const float*)d_in[7];
    const float* bhh   = (const float*)d_in[8];
    float* out = (float*)d_out;
    const int N = in_sizes[0] / 3;

    // ws (shorts): wh 327680 | whh 81920 | gf 20480   (0.86 MB)
    short* wh  = (short*)d_ws;
    short* whh = wh + 327680;
    short* gf  = whh + 81920;

    ffb_pack<<<210, 256, 0, stream>>>(Wh, Whh, ffnA, wh, whh, gf);
    ffb_main<<<N / TM, 256, 0, stream>>>(pos, gfeat, W0, b0, bh, bhh,
                                         wh, whh, gf, out);
}